// Round 4
// baseline (648.961 us; speedup 1.0000x reference)
//
#include <hip/hip_runtime.h>
#include <math.h>

#define NN 50000
#define EE 800000
#define NB 196   // ceil(NN/256)

typedef _Float16 half8 __attribute__((ext_vector_type(8)));
typedef _Float16 hv4  __attribute__((ext_vector_type(4)));
typedef _Float16 hv2  __attribute__((ext_vector_type(2)));
typedef __fp16 fp16v2 __attribute__((ext_vector_type(2)));
typedef float floatx16 __attribute__((ext_vector_type(16)));
typedef float fv4 __attribute__((ext_vector_type(4)));

__device__ __forceinline__ float fexp2(float x) { return __builtin_amdgcn_exp2f(x); }

// DPP row_ror all-reduce within 16-lane rows: rotations by 1,2,4,8.
template<int CTRL>
__device__ __forceinline__ float dppadd(float x) {
    int t = __builtin_amdgcn_update_dpp(0, __float_as_int(x), CTRL, 0xf, 0xf, false);
    return x + __int_as_float(t);
}
__device__ __forceinline__ float red16(float x) {
    x = dppadd<0x121>(x);   // row_ror:1
    x = dppadd<0x122>(x);   // row_ror:2
    x = dppadd<0x124>(x);   // row_ror:4
    x = dppadd<0x128>(x);   // row_ror:8
    return x;
}

// fp16 helpers -----------------------------------------------------
// RTN duplicated-pack (accuracy path, used in prep/table kernels)
__device__ __forceinline__ unsigned int dup16(float x) {
    unsigned short b = __builtin_bit_cast(unsigned short, (_Float16)x);
    return (unsigned int)b * 0x10001u;
}
// fast duplicated-pack (hot loop, RTZ ok for softmax weights)
__device__ __forceinline__ unsigned int duph(float x) {
#if __has_builtin(__builtin_amdgcn_cvt_pkrtz)
    fp16v2 p = __builtin_amdgcn_cvt_pkrtz(x, x);
    return __builtin_bit_cast(unsigned int, p);
#else
    return dup16(x);
#endif
}
// broadcast a packed half2 dword to an hv4 (ISel reuses the same dword)
__device__ __forceinline__ hv4 b4(unsigned int u) {
    hv2 p = __builtin_bit_cast(hv2, u);
    return (hv4){p[0], p[1], p[0], p[1]};
}
// 4-element fp16 dot accumulating into f32 (v_dot2_f32_f16 x2)
__device__ __forceinline__ float dot4h(hv4 a, hv4 b, float c) {
    hv2 al = {a[0], a[1]}, ah = {a[2], a[3]};
    hv2 bl = {b[0], b[1]}, bh = {b[2], b[3]};
#if __has_builtin(__builtin_amdgcn_fdot2)
    return __builtin_amdgcn_fdot2(al, bl, __builtin_amdgcn_fdot2(ah, bh, c, false), false);
#else
    return c + (float)a[0]*(float)b[0] + (float)a[1]*(float)b[1]
             + (float)a[2]*(float)b[2] + (float)a[3]*(float)b[3];
#endif
}

// ------------------------------------------------------------------
// Swizzle A (fp32 row-major M x K) into 32x32x16 MFMA A-fragment order.
// ------------------------------------------------------------------
__global__ __launch_bounds__(256) void swizzleA(
    const float* __restrict__ A, _Float16* __restrict__ Asw, int M, int K)
{
    int wave = threadIdx.x >> 6, lane = threadIdx.x & 63;
    int tile = blockIdx.x;
    int kc = blockIdx.y * 4 + wave;
    int KC = K >> 4;
    if (kc >= KC) return;
    int row = tile * 32 + (lane & 31);
    int k0 = kc * 16 + (lane >> 5) * 8;
    float4 v0 = make_float4(0.f, 0.f, 0.f, 0.f);
    float4 v1 = make_float4(0.f, 0.f, 0.f, 0.f);
    if (row < M) {
        const float* p = A + (size_t)row * K + k0;
        v0 = *(const float4*)p;
        v1 = *(const float4*)(p + 4);
    }
    half8 o;
    o[0] = (_Float16)v0.x; o[1] = (_Float16)v0.y;
    o[2] = (_Float16)v0.z; o[3] = (_Float16)v0.w;
    o[4] = (_Float16)v1.x; o[5] = (_Float16)v1.y;
    o[6] = (_Float16)v1.z; o[7] = (_Float16)v1.w;
    *(half8*)(Asw + (((size_t)tile * KC + kc) * 64 + lane) * 8) = o;
}

// ------------------------------------------------------------------
// All weight swizzles + bias concats + fp16 We/att conversion, one dispatch.
// ------------------------------------------------------------------
__global__ __launch_bounds__(256) void prep_weights(
    const float* __restrict__ s0, const float* __restrict__ s1,
    const float* __restrict__ s2, const float* __restrict__ s3,
    const float* __restrict__ s4, const float* __restrict__ s5,
    const float* __restrict__ s6, const float* __restrict__ s7,
    _Float16* __restrict__ catB0, _Float16* __restrict__ catB1,
    _Float16* __restrict__ catB2,
    const float* __restrict__ bl0, const float* __restrict__ br0,
    const float* __restrict__ pb0, const float* __restrict__ bl1,
    const float* __restrict__ br1, const float* __restrict__ bl2,
    const float* __restrict__ br2, const float* __restrict__ pb2,
    float* __restrict__ cb0, float* __restrict__ cb1, float* __restrict__ cb2,
    const float* __restrict__ We0a, const float* __restrict__ We1a,
    const float* __restrict__ We2a, const float* __restrict__ att0a,
    const float* __restrict__ att1a, const float* __restrict__ att2a,
    _Float16* __restrict__ Weh)
{
    int b = blockIdx.x;
    if (b == 192) {   // fp16 conversion of We (1280) + att (256) per layer
        const float* Ws[3] = {We0a, We1a, We2a};
        const float* As[3] = {att0a, att1a, att2a};
        for (int t = threadIdx.x; t < 4608; t += 256) {
            int l = t / 1536, o = t - l * 1536;
            float v = (o < 1280) ? Ws[l][o] : As[l][o - 1280];
            Weh[t] = (_Float16)v;
        }
        return;
    }
    if (b >= 184) {
        int t = (b - 184) * 256 + threadIdx.x;   // 0..2047
        if (t < 768) {
            cb0[t] = (t < 256) ? bl0[t] : (t < 512) ? br0[t - 256] : pb0[t - 512];
        } else if (t < 1280) {
            int u = t - 768;
            cb1[u] = (u < 256) ? bl1[u] : br1[u - 256];
        } else if (t < 1856) {
            int u = t - 1280;
            cb2[u] = (u < 256) ? bl2[u] : (u < 512) ? br2[u - 256] : pb2[u - 512];
        }
        return;
    }
    int wave = threadIdx.x >> 6, lane = threadIdx.x & 63;
    int pair = b * 4 + wave;     // 0..735
    const int cum[9] = {0, 64, 128, 192, 320, 448, 576, 704, 736};
    int job = 0;
    while (pair >= cum[job + 1]) ++job;
    const float* srcs[8] = {s0, s1, s2, s3, s4, s5, s6, s7};
    const int KCs[8] = {8, 8, 8, 16, 16, 16, 16, 16};
    const int NCs[8] = {256, 256, 256, 256, 256, 256, 256, 64};
    const int ntb[8] = {0, 8, 16, 0, 8, 0, 8, 16};
    _Float16* dsts[8] = {catB0, catB0, catB0, catB1, catB1, catB2, catB2, catB2};
    int p = pair - cum[job];
    int KC = KCs[job], NC = NCs[job];
    int nt = p / KC, kc = p - nt * KC;
    int n = (nt >> 1) * 64 + ((lane & 31) * 2) + (nt & 1);
    int k0 = kc * 16 + (lane >> 5) * 8;
    const float* B = srcs[job];
    half8 o;
#pragma unroll
    for (int jj = 0; jj < 8; ++jj)
        o[jj] = (_Float16)B[(size_t)(k0 + jj) * NC + n];
    int ntG = ntb[job] + nt;
    *(half8*)(dsts[job] + (((size_t)ntG * KC + kc) * 64 + lane) * 8) = o;
}

// ------------------------------------------------------------------
// MFMA GEMM: block = 64 rows x 256 cols. All 4 waves share the SAME
// two A row-tiles (16KB -> L1-resident, loaded from L2/HBM once per
// block); each wave owns one 64-col group. Halves device A-traffic
// vs the previous 128x128 mapping (A re-read NG/4 x instead of NG/2 x).
// ------------------------------------------------------------------
__global__ __launch_bounds__(256) void gemm_mfma(
    const _Float16* __restrict__ Asw, const _Float16* __restrict__ Bsw,
    const float* __restrict__ bias, _Float16* __restrict__ C,
    int M, int K, int NC)
{
    const int wave = threadIdx.x >> 6, lane = threadIdx.x & 63;
    const int KC = K >> 4;
    const int rt0 = blockIdx.x * 2;       // 2 row-tiles (64 rows) per block
    const int NG = NC >> 6;
    int g = blockIdx.y * 4 + wave;        // one 64-col group per wave
    if (g >= NG) g = NG - 1;              // duplicate work for odd group counts

    const half8* Ap0 = (const half8*)Asw + (size_t)rt0 * KC * 64 + lane;
    const half8* Ap1 = Ap0 + (size_t)KC * 64;
    const half8* Bp0 = (const half8*)Bsw + (size_t)(2 * g) * KC * 64 + lane;
    const half8* Bp1 = Bp0 + (size_t)KC * 64;

    floatx16 accE0 = {0.f}, accE1 = {0.f}, accO0 = {0.f}, accO1 = {0.f};

#pragma unroll 4
    for (int kc = 0; kc < KC; ++kc) {
        half8 a0 = Ap0[(size_t)kc * 64];
        half8 a1 = Ap1[(size_t)kc * 64];
        half8 b0 = Bp0[(size_t)kc * 64];
        half8 b1 = Bp1[(size_t)kc * 64];
        accE0 = __builtin_amdgcn_mfma_f32_32x32x16_f16(a0, b0, accE0, 0, 0, 0);
        accE1 = __builtin_amdgcn_mfma_f32_32x32x16_f16(a1, b0, accE1, 0, 0, 0);
        accO0 = __builtin_amdgcn_mfma_f32_32x32x16_f16(a0, b1, accO0, 0, 0, 0);
        accO1 = __builtin_amdgcn_mfma_f32_32x32x16_f16(a1, b1, accO1, 0, 0, 0);
    }

    const int nlane = lane & 31, hs = lane >> 5;
    int colb = g * 64 + nlane * 2;
    float be = bias[colb], bo = bias[colb + 1];
#pragma unroll
    for (int r = 0; r < 16; ++r) {
        int rowin = (r & 3) + 8 * (r >> 2) + 4 * hs;
        int row0 = rt0 * 32 + rowin;
        int row1 = row0 + 32;
        if (row0 < M) {
            hv2 pe;
            pe[0] = (_Float16)(accE0[r] + be);
            pe[1] = (_Float16)(accO0[r] + bo);
            *(hv2*)(C + (size_t)row0 * NC + colb) = pe;
        }
        if (row1 < M) {
            hv2 po;
            po[0] = (_Float16)(accE1[r] + be);
            po[1] = (_Float16)(accO1[r] + bo);
            *(hv2*)(C + (size_t)row1 * NC + colb) = po;
        }
    }
}

// ------------------------------------------------------------------
// CSR build: histogram -> two-level scan -> scatter
// ------------------------------------------------------------------
__global__ __launch_bounds__(256) void hist_kernel(const int* __restrict__ dst,
                                                   int* __restrict__ deg)
{
    int e = blockIdx.x * 256 + threadIdx.x;
    if (e < EE) atomicAdd(&deg[dst[e]], 1);
}

__global__ __launch_bounds__(256) void scan_local(const int* __restrict__ deg,
                                                  int* __restrict__ rowoff,
                                                  int* __restrict__ part)
{
    __shared__ int sd[256];
    int tid = threadIdx.x;
    int i = blockIdx.x * 256 + tid;
    int v = (i < NN) ? deg[i] : 0;
    sd[tid] = v;
    __syncthreads();
    for (int off = 1; off < 256; off <<= 1) {
        int t = (tid >= off) ? sd[tid - off] : 0;
        __syncthreads();
        sd[tid] += t;
        __syncthreads();
    }
    if (i < NN) rowoff[i] = sd[tid] - v;
    if (tid == 255) part[blockIdx.x] = sd[255];
}

__global__ __launch_bounds__(256) void scan_part(int* __restrict__ part,
                                                 int* __restrict__ rowoff)
{
    __shared__ int sd[256];
    int tid = threadIdx.x;
    int v = (tid < NB) ? part[tid] : 0;
    sd[tid] = v;
    __syncthreads();
    for (int off = 1; off < 256; off <<= 1) {
        int t = (tid >= off) ? sd[tid - off] : 0;
        __syncthreads();
        sd[tid] += t;
        __syncthreads();
    }
    if (tid < NB) part[tid] = sd[tid] - v;
    if (tid == 0) rowoff[NN] = EE;
}

__global__ __launch_bounds__(256) void scan_add(int* __restrict__ rowoff,
                                                const int* __restrict__ part,
                                                int* __restrict__ cursor)
{
    int i = blockIdx.x * 256 + threadIdx.x;
    if (i < NN) {
        rowoff[i] += part[blockIdx.x];
        cursor[i] = 0;
    }
}

// scatter: CSR edge data; attrs stored as fp16 duplicated-pack dwords
__global__ __launch_bounds__(256) void scatter_kernel(
    const int* __restrict__ src, const int* __restrict__ dst,
    const float* __restrict__ ea, const int* __restrict__ rowoff,
    int* __restrict__ cursor, int* __restrict__ srcp,
    unsigned int* __restrict__ apk, float* __restrict__ erec)
{
    int e = blockIdx.x * 256 + threadIdx.x;
    if (e < EE) {
        int d = dst[e];
        int pos = rowoff[d] + atomicAdd(&cursor[d], 1);
        srcp[pos] = src[e];
        const float* p = ea + (size_t)e * 5;
        uint4 o;
        o.x = dup16(p[0]); o.y = dup16(p[1]);
        o.z = dup16(p[2]); o.w = dup16(p[3]);
        *(uint4*)(apk + (size_t)pos * 4) = o;
        erec[pos] = 1.0f / fmaxf(p[3], 1e-6f);
    }
}

// ------------------------------------------------------------------
// Per-layer physics-term table: q = temp/|Z| is unbounded, so the fp16
// score chain uses the homogeneity rescale  s = max(1, q/64):
//   m' = inv_s*(xl+xr+sum ak*wwk) + min(q,64)*ww4 ;  logit = s*dot(att,LR(m'))
// Table per edge: {qs_pk, inv_pk, s*log2e (f32), pad} = 16 B.
// ------------------------------------------------------------------
__global__ __launch_bounds__(256) void build_qtab(
    const float* __restrict__ erec, const float* __restrict__ temp,
    unsigned int* __restrict__ qtab)
{
    int e = blockIdx.x * 256 + threadIdx.x;
    if (e >= EE) return;
    float q = temp[0] * erec[e];
    float qs = fminf(q, 64.f);
    float inv = (q > 64.f) ? 64.f * __builtin_amdgcn_rcpf(q) : 1.0f;
    float sl = fmaxf(q * 0.015625f, 1.f) * 1.44269504088896340736f;
    uint4 o;
    o.x = dup16(qs);
    o.y = dup16(inv);
    o.z = __builtin_bit_cast(unsigned int, sl);
    o.w = 0u;
    *(uint4*)(qtab + (size_t)e * 4) = o;
}

// ------------------------------------------------------------------
// Fused GATv2 + LayerNorm + residual (+ELU) + A-swizzle for next GEMM.
// One wave per node. Edge-score chain in packed fp16 (v_pk_* at 2x f32
// rate), logit via v_dot2_f32_f16, softmax state in f32, weighted-sum
// accumulated in fp16 per 4-edge group and merged into f32 acc.
// (Round-2 proven loop structure; 8-deep/2-state variant measured
// slower -- kernel is fabric-BW bound, not dep-chain bound.)
// ------------------------------------------------------------------
template<int MODE, int RSTRIDE>
__global__ __launch_bounds__(256) void fused_attn_ln(
    const int* __restrict__ rowoff, const int* __restrict__ srcp,
    const unsigned int* __restrict__ apk, const unsigned int* __restrict__ qtab,
    const _Float16* __restrict__ xlp, const _Float16* __restrict__ Wh,
    const float* __restrict__ bias, const float* __restrict__ lnw,
    const float* __restrict__ lnb,
    const _Float16* __restrict__ residH, const float* __restrict__ residF,
    float* __restrict__ outF, _Float16* __restrict__ aswOut)
{
    int v = __builtin_amdgcn_readfirstlane(blockIdx.x * 4 + (threadIdx.x >> 6));
    int lane = threadIdx.x & 63;
    if (v >= NN) return;
    int grp = lane >> 4;
    int sub = lane & 15;
    int j = grp * 64 + sub * 4;

    hv4 ww0h = *(const hv4*)(Wh + j);
    hv4 ww1h = *(const hv4*)(Wh + 256 + j);
    hv4 ww2h = *(const hv4*)(Wh + 512 + j);
    hv4 ww3h = *(const hv4*)(Wh + 768 + j);
    hv4 ww4h = *(const hv4*)(Wh + 1024 + j);
    hv4 atvh = *(const hv4*)(Wh + 1280 + j);
    hv4 xrvh = *(const hv4*)(xlp + (size_t)v * RSTRIDE + 256 + j);
    const _Float16 s02 = (_Float16)0.2f;
    const hv4 sl02 = {s02, s02, s02, s02};
    const float L2E = 1.44269504088896340736f;

    float mxd = -INFINITY, dend = 0.f;
    fv4 acc = {0.f, 0.f, 0.f, 0.f};

    int beg = __builtin_amdgcn_readfirstlane(rowoff[v]);
    int end = __builtin_amdgcn_readfirstlane(rowoff[v + 1]);
    int i = beg;
    for (; i + 4 <= end; i += 4) {
        int s[4]; uint4 ap[4], qt[4]; hv4 xh[4]; float l[4];
#pragma unroll
        for (int u = 0; u < 4; ++u) {
            s[u] = __builtin_amdgcn_readfirstlane(srcp[i + u]);
            ap[u] = *(const uint4*)(apk + (size_t)(i + u) * 4);
            qt[u] = *(const uint4*)(qtab + (size_t)(i + u) * 4);
        }
#pragma unroll
        for (int u = 0; u < 4; ++u)
            xh[u] = *(const hv4*)(xlp + (size_t)s[u] * RSTRIDE + j);
#pragma unroll
        for (int u = 0; u < 4; ++u) {
            hv4 t = xh[u] + xrvh;                 // xl[src] + xr[dst]
            t += b4(ap[u].x) * ww0h;
            t += b4(ap[u].y) * ww1h;
            t += b4(ap[u].z) * ww2h;
            t += b4(ap[u].w) * ww3h;
            hv4 m = b4(qt[u].x) * ww4h;           // min(q,64)*ww4
            m += b4(qt[u].y) * t;                 // + inv_s*(...)
            hv4 mn = m * sl02;
            m = __builtin_elementwise_max(m, mn); // leaky_relu (homogeneous)
            l[u] = dot4h(m, atvh, 0.f);
        }
#pragma unroll
        for (int u = 0; u < 4; ++u)
            l[u] = red16(l[u]) * __builtin_bit_cast(float, qt[u].z);  // *s*log2e
        float nm = fmaxf(fmaxf(l[0], l[1]), fmaxf(l[2], l[3]));
        nm = fmaxf(nm, mxd);
        float sc = fexp2(mxd - nm);
        float e0 = fexp2(l[0] - nm);
        float e1 = fexp2(l[1] - nm);
        float e2 = fexp2(l[2] - nm);
        float e3 = fexp2(l[3] - nm);
        mxd = nm;
        dend = dend * sc + ((e0 + e1) + (e2 + e3));
        hv4 X = xh[0] * b4(duph(e0));
        X += xh[1] * b4(duph(e1));
        X += xh[2] * b4(duph(e2));
        X += xh[3] * b4(duph(e3));
        fv4 Xf = __builtin_convertvector(X, fv4);
        acc = acc * sc + Xf;
    }
    for (; i < end; ++i) {
        int s0 = __builtin_amdgcn_readfirstlane(srcp[i]);
        uint4 ap = *(const uint4*)(apk + (size_t)i * 4);
        uint4 qt = *(const uint4*)(qtab + (size_t)i * 4);
        hv4 xh = *(const hv4*)(xlp + (size_t)s0 * RSTRIDE + j);
        hv4 t = xh + xrvh;
        t += b4(ap.x) * ww0h;
        t += b4(ap.y) * ww1h;
        t += b4(ap.z) * ww2h;
        t += b4(ap.w) * ww3h;
        hv4 m = b4(qt.x) * ww4h;
        m += b4(qt.y) * t;
        hv4 mn = m * sl02;
        m = __builtin_elementwise_max(m, mn);
        float l0 = dot4h(m, atvh, 0.f);
        l0 = red16(l0) * __builtin_bit_cast(float, qt.z);
        float nm = fmaxf(mxd, l0);
        float sc = fexp2(mxd - nm);
        float e0 = fexp2(l0 - nm);
        mxd = nm;
        dend = dend * sc + e0;
        fv4 xf = __builtin_convertvector(xh, fv4);
        acc = acc * sc + xf * e0;
    }

    float inv = __builtin_amdgcn_rcpf(dend + 1e-16f);
    if (MODE <= 1) {
        fv4 bb = *(const fv4*)(bias + j);
        fv4 o = acc * inv + bb;
        float s  = (o[0] + o[1]) + (o[2] + o[3]);
        fv4 oq = o * o;
        float s2 = (oq[0] + oq[1]) + (oq[2] + oq[3]);
        s = red16(s);   s += __shfl_xor(s, 16, 64);  s += __shfl_xor(s, 32, 64);
        s2 = red16(s2); s2 += __shfl_xor(s2, 16, 64); s2 += __shfl_xor(s2, 32, 64);
        float mu = s * (1.f / 256.f);
        float var = s2 * (1.f / 256.f) - mu * mu;
        float rs = __builtin_amdgcn_rsqf(var + 1e-5f);
        fv4 lw = *(const fv4*)(lnw + j);
        fv4 lb = *(const fv4*)(lnb + j);
        fv4 rr;
        if (MODE == 0)
            rr = __builtin_convertvector(
                *(const hv4*)(residH + (size_t)v * RSTRIDE + j), fv4);
        else
            rr = *(const fv4*)(residF + (size_t)v * 256 + j);
        fv4 y = (o - mu) * rs * lw + lb + rr;
        y[0] = (y[0] > 0.f) ? y[0] : fexp2(y[0] * L2E) - 1.f;
        y[1] = (y[1] > 0.f) ? y[1] : fexp2(y[1] * L2E) - 1.f;
        y[2] = (y[2] > 0.f) ? y[2] : fexp2(y[2] * L2E) - 1.f;
        y[3] = (y[3] > 0.f) ? y[3] : fexp2(y[3] * L2E) - 1.f;
        if (MODE == 0)
            *(fv4*)(outF + (size_t)v * 256 + j) = y;
        // fused A-swizzle for the next layer's GEMM (K=256, KC=16)
        int kc = j >> 4, half = (j >> 3) & 1, off = j & 7;
        size_t idx = (((size_t)(v >> 5) * 16 + kc) * 64 + (v & 31) + 32 * half) * 8 + off;
        hv4 yh = __builtin_convertvector(y, hv4);
        *(hv4*)(aswOut + idx) = yh;
    } else {
        fv4 r = acc * inv;
        r[0] += __shfl_xor(r[0], 16, 64); r[0] += __shfl_xor(r[0], 32, 64);
        r[1] += __shfl_xor(r[1], 16, 64); r[1] += __shfl_xor(r[1], 32, 64);
        r[2] += __shfl_xor(r[2], 16, 64); r[2] += __shfl_xor(r[2], 32, 64);
        r[3] += __shfl_xor(r[3], 16, 64); r[3] += __shfl_xor(r[3], 32, 64);
        fv4 bb = *(const fv4*)(bias + sub * 4);
        fv4 o = r * 0.25f + bb;
        float s  = (o[0] + o[1]) + (o[2] + o[3]);
        fv4 oq = o * o;
        float s2 = (oq[0] + oq[1]) + (oq[2] + oq[3]);
        s = red16(s);
        s2 = red16(s2);
        float mu = s * (1.f / 64.f);
        float var = s2 * (1.f / 64.f) - mu * mu;
        float rs = __builtin_amdgcn_rsqf(var + 1e-5f);
        fv4 lw = *(const fv4*)(lnw + sub * 4);
        fv4 lb = *(const fv4*)(lnb + sub * 4);
        fv4 rr = __builtin_convertvector(
            *(const hv4*)(residH + (size_t)v * RSTRIDE + sub * 4), fv4);
        fv4 y = (o - mu) * rs * lw + lb + rr;
        if (grp == 0)
            *(fv4*)(outF + (size_t)v * 64 + sub * 4) = y;
    }
}

// ------------------------------------------------------------------
extern "C" void kernel_launch(void* const* d_in, const int* in_sizes, int n_in,
                              void* d_out, int out_size, void* d_ws, size_t ws_size,
                              hipStream_t stream)
{
    const float* x    = (const float*)d_in[0];
    const int*   eidx = (const int*)d_in[1];
    const float* ea   = (const float*)d_in[2];
    const int* src = eidx;
    const int* dst = eidx + EE;

    const float *Wl[3], *bl[3], *Wr[3], *br[3], *We[3], *att[3], *temp[3],
                *bias[3], *lnw[3], *lnb[3];
    for (int i = 0; i < 3; ++i) {
        int b = 3 + i * 10;
        Wl[i]   = (const float*)d_in[b + 0];
        bl[i]   = (const float*)d_in[b + 1];
        Wr[i]   = (const float*)d_in[b + 2];
        br[i]   = (const float*)d_in[b + 3];
        We[i]   = (const float*)d_in[b + 4];
        att[i]  = (const float*)d_in[b + 5];
        temp[i] = (const float*)d_in[b + 6];
        bias[i] = (const float*)d_in[b + 7];
        lnw[i]  = (const float*)d_in[b + 8];
        lnb[i]  = (const float*)d_in[b + 9];
    }
    const float* pw0 = (const float*)d_in[33];
    const float* pb0 = (const float*)d_in[34];
    const float* pw2 = (const float*)d_in[35];
    const float* pb2 = (const float*)d_in[36];

    // workspace carve-up
    char* w = (char*)d_ws;
    float* h     = (float*)w; w += (size_t)NN * 256 * 4;          // 51.2 MB
    char*  gbase = w;         w += (size_t)NN * 256 * 4;          // Asw (<=25.7MB) + qtab
    _Float16* xlr = (_Float16*)w; w += (size_t)NN * 768 * 2;      // 76.8 MB
    unsigned int* apk = (unsigned int*)w; w += (size_t)EE * 16;   // fp16-pk attrs
    float* erec  = (float*)w; w += (size_t)EE * 4;
    int* srcp    = (int*)w;   w += (size_t)EE * 4;
    int* rowoff  = (int*)w;   w += (size_t)(NN + 16) * 4;
    int* cursor  = (int*)w;   w += (size_t)NN * 4;
    int* part    = (int*)w;   w += 1024;
    w = (char*)(((uintptr_t)w + 255) & ~(uintptr_t)255);
    _Float16* catB0 = (_Float16*)w; w += 196608;   // 24 nt x  8 kc x 512 h
    _Float16* catB1 = (_Float16*)w; w += 262144;   // 16 nt x 16 kc
    _Float16* catB2 = (_Float16*)w; w += 294912;   // 18 nt x 16 kc
    float* cb0 = (float*)w; w += 768 * 4;
    float* cb1 = (float*)w; w += 512 * 4;
    float* cb2 = (float*)w; w += 576 * 4;
    _Float16* Weh = (_Float16*)w; w += 4608 * 2;   // fp16 We+att, 3 layers
    _Float16* Asw = (_Float16*)gbase;              // max 25.62 MB used
    unsigned int* qtab = (unsigned int*)(gbase + 38400000); // 12.8 MB, no overlap

    dim3 blk(256);
    dim3 grid_e((EE + 255) / 256);
    dim3 grid_nw((NN + 3) / 4);
    dim3 grid_nb(NB);
    const int MT2 = 782;   // ceil(50000/64) -> 64-row blocks

    // ---- CSR by dst (shared by all 3 layers) ----
    hipMemsetAsync(cursor, 0, (size_t)NN * 4, stream);
    hipLaunchKernelGGL(hist_kernel, grid_e, blk, 0, stream, dst, cursor);
    hipLaunchKernelGGL(scan_local, grid_nb, blk, 0, stream, cursor, rowoff, part);
    hipLaunchKernelGGL(scan_part, dim3(1), blk, 0, stream, part, rowoff);
    hipLaunchKernelGGL(scan_add, grid_nb, blk, 0, stream, rowoff, part, cursor);
    hipLaunchKernelGGL(scatter_kernel, grid_e, blk, 0, stream,
                       src, dst, ea, rowoff, cursor, srcp, apk, erec);

    // ---- all weight swizzles + bias concats + fp16 We/att, one dispatch ----
    hipLaunchKernelGGL(prep_weights, dim3(193), blk, 0, stream,
                       Wl[0], Wr[0], pw0, Wl[1], Wr[1], Wl[2], Wr[2], pw2,
                       catB0, catB1, catB2,
                       bl[0], br[0], pb0, bl[1], br[1], bl[2], br[2], pb2,
                       cb0, cb1, cb2,
                       We[0], We[1], We[2], att[0], att[1], att[2], Weh);

    // ---- Layer 0: swizzle x, one GEMM -> [xl|xr|res] fp16 rows of 768 ----
    swizzleA<<<dim3(1564, 2), blk, 0, stream>>>(x, Asw, NN, 128);
    hipLaunchKernelGGL(build_qtab, grid_e, blk, 0, stream, erec, temp[0], qtab);
    gemm_mfma<<<dim3(MT2, 3), blk, 0, stream>>>(
        Asw, catB0, cb0, xlr, NN, 128, 768);
    fused_attn_ln<0, 768><<<grid_nw, blk, 0, stream>>>(
        rowoff, srcp, apk, qtab, xlr, Weh,
        bias[0], lnw[0], lnb[0], xlr + 512, nullptr, h, Asw);

    // ---- Layer 1: one GEMM -> [xl|xr] rows of 512; resid = h ----
    hipLaunchKernelGGL(build_qtab, grid_e, blk, 0, stream, erec, temp[1], qtab);
    gemm_mfma<<<dim3(MT2, 2), blk, 0, stream>>>(
        Asw, catB1, cb1, xlr, NN, 256, 512);
    fused_attn_ln<1, 512><<<grid_nw, blk, 0, stream>>>(
        rowoff, srcp, apk, qtab, xlr, Weh + 1536,
        bias[1], lnw[1], lnb[1], nullptr, h, h, Asw);

    // ---- Layer 2: single GEMM -> [xl|xr|res64] rows of 576 (9 groups) ----
    hipLaunchKernelGGL(build_qtab, grid_e, blk, 0, stream, erec, temp[2], qtab);
    gemm_mfma<<<dim3(MT2, 3), blk, 0, stream>>>(
        Asw, catB2, cb2, xlr, NN, 256, 576);
    fused_attn_ln<2, 576><<<grid_nw, blk, 0, stream>>>(
        rowoff, srcp, apk, qtab, xlr, Weh + 3072,
        bias[2], lnw[2], lnb[2], xlr + 512, nullptr, (float*)d_out, nullptr);
}

// Round 5
// 626.422 us; speedup vs baseline: 1.0360x; 1.0360x over previous
//
#include <hip/hip_runtime.h>
#include <math.h>

#define NN 50000
#define EE 800000
#define NB 196   // ceil(NN/256)

typedef _Float16 half8 __attribute__((ext_vector_type(8)));
typedef _Float16 hv4  __attribute__((ext_vector_type(4)));
typedef _Float16 hv2  __attribute__((ext_vector_type(2)));
typedef __fp16 fp16v2 __attribute__((ext_vector_type(2)));
typedef float floatx16 __attribute__((ext_vector_type(16)));
typedef float fv4 __attribute__((ext_vector_type(4)));

__device__ __forceinline__ float fexp2(float x) { return __builtin_amdgcn_exp2f(x); }

// DPP row_ror all-reduce within 16-lane rows: rotations by 1,2,4,8.
template<int CTRL>
__device__ __forceinline__ float dppadd(float x) {
    int t = __builtin_amdgcn_update_dpp(0, __float_as_int(x), CTRL, 0xf, 0xf, false);
    return x + __int_as_float(t);
}
__device__ __forceinline__ float red16(float x) {
    x = dppadd<0x121>(x);   // row_ror:1
    x = dppadd<0x122>(x);   // row_ror:2
    x = dppadd<0x124>(x);   // row_ror:4
    x = dppadd<0x128>(x);   // row_ror:8
    return x;
}

// fp16 helpers -----------------------------------------------------
// RTN duplicated-pack (accuracy path, used in prep/scatter kernels)
__device__ __forceinline__ unsigned int dup16(float x) {
    unsigned short b = __builtin_bit_cast(unsigned short, (_Float16)x);
    return (unsigned int)b * 0x10001u;
}
// fast duplicated-pack (hot loop, RTZ ok)
__device__ __forceinline__ unsigned int duph(float x) {
#if __has_builtin(__builtin_amdgcn_cvt_pkrtz)
    fp16v2 p = __builtin_amdgcn_cvt_pkrtz(x, x);
    return __builtin_bit_cast(unsigned int, p);
#else
    return dup16(x);
#endif
}
// broadcast a packed half2 dword to an hv4 (ISel reuses the same dword)
__device__ __forceinline__ hv4 b4(unsigned int u) {
    hv2 p = __builtin_bit_cast(hv2, u);
    return (hv4){p[0], p[1], p[0], p[1]};
}
// 4-element fp16 dot accumulating into f32 (v_dot2_f32_f16 x2)
__device__ __forceinline__ float dot4h(hv4 a, hv4 b, float c) {
    hv2 al = {a[0], a[1]}, ah = {a[2], a[3]};
    hv2 bl = {b[0], b[1]}, bh = {b[2], b[3]};
#if __has_builtin(__builtin_amdgcn_fdot2)
    return __builtin_amdgcn_fdot2(al, bl, __builtin_amdgcn_fdot2(ah, bh, c, false), false);
#else
    return c + (float)a[0]*(float)b[0] + (float)a[1]*(float)b[1]
             + (float)a[2]*(float)b[2] + (float)a[3]*(float)b[3];
#endif
}

// ------------------------------------------------------------------
// Swizzle A (fp32 row-major M x K) into 32x32x16 MFMA A-fragment order.
// ------------------------------------------------------------------
__global__ __launch_bounds__(256) void swizzleA(
    const float* __restrict__ A, _Float16* __restrict__ Asw, int M, int K)
{
    int wave = threadIdx.x >> 6, lane = threadIdx.x & 63;
    int tile = blockIdx.x;
    int kc = blockIdx.y * 4 + wave;
    int KC = K >> 4;
    if (kc >= KC) return;
    int row = tile * 32 + (lane & 31);
    int k0 = kc * 16 + (lane >> 5) * 8;
    float4 v0 = make_float4(0.f, 0.f, 0.f, 0.f);
    float4 v1 = make_float4(0.f, 0.f, 0.f, 0.f);
    if (row < M) {
        const float* p = A + (size_t)row * K + k0;
        v0 = *(const float4*)p;
        v1 = *(const float4*)(p + 4);
    }
    half8 o;
    o[0] = (_Float16)v0.x; o[1] = (_Float16)v0.y;
    o[2] = (_Float16)v0.z; o[3] = (_Float16)v0.w;
    o[4] = (_Float16)v1.x; o[5] = (_Float16)v1.y;
    o[6] = (_Float16)v1.z; o[7] = (_Float16)v1.w;
    *(half8*)(Asw + (((size_t)tile * KC + kc) * 64 + lane) * 8) = o;
}

// ------------------------------------------------------------------
// All weight swizzles + bias concats + fp16 We/att conversion, one dispatch.
// ------------------------------------------------------------------
__global__ __launch_bounds__(256) void prep_weights(
    const float* __restrict__ s0, const float* __restrict__ s1,
    const float* __restrict__ s2, const float* __restrict__ s3,
    const float* __restrict__ s4, const float* __restrict__ s5,
    const float* __restrict__ s6, const float* __restrict__ s7,
    _Float16* __restrict__ catB0, _Float16* __restrict__ catB1,
    _Float16* __restrict__ catB2,
    const float* __restrict__ bl0, const float* __restrict__ br0,
    const float* __restrict__ pb0, const float* __restrict__ bl1,
    const float* __restrict__ br1, const float* __restrict__ bl2,
    const float* __restrict__ br2, const float* __restrict__ pb2,
    float* __restrict__ cb0, float* __restrict__ cb1, float* __restrict__ cb2,
    const float* __restrict__ We0a, const float* __restrict__ We1a,
    const float* __restrict__ We2a, const float* __restrict__ att0a,
    const float* __restrict__ att1a, const float* __restrict__ att2a,
    _Float16* __restrict__ Weh)
{
    int b = blockIdx.x;
    if (b == 192) {   // fp16 conversion of We (1280) + att (256) per layer
        const float* Ws[3] = {We0a, We1a, We2a};
        const float* As[3] = {att0a, att1a, att2a};
        for (int t = threadIdx.x; t < 4608; t += 256) {
            int l = t / 1536, o = t - l * 1536;
            float v = (o < 1280) ? Ws[l][o] : As[l][o - 1280];
            Weh[t] = (_Float16)v;
        }
        return;
    }
    if (b >= 184) {
        int t = (b - 184) * 256 + threadIdx.x;   // 0..2047
        if (t < 768) {
            cb0[t] = (t < 256) ? bl0[t] : (t < 512) ? br0[t - 256] : pb0[t - 512];
        } else if (t < 1280) {
            int u = t - 768;
            cb1[u] = (u < 256) ? bl1[u] : br1[u - 256];
        } else if (t < 1856) {
            int u = t - 1280;
            cb2[u] = (u < 256) ? bl2[u] : (u < 512) ? br2[u - 256] : pb2[u - 512];
        }
        return;
    }
    int wave = threadIdx.x >> 6, lane = threadIdx.x & 63;
    int pair = b * 4 + wave;     // 0..735
    const int cum[9] = {0, 64, 128, 192, 320, 448, 576, 704, 736};
    int job = 0;
    while (pair >= cum[job + 1]) ++job;
    const float* srcs[8] = {s0, s1, s2, s3, s4, s5, s6, s7};
    const int KCs[8] = {8, 8, 8, 16, 16, 16, 16, 16};
    const int NCs[8] = {256, 256, 256, 256, 256, 256, 256, 64};
    const int ntb[8] = {0, 8, 16, 0, 8, 0, 8, 16};
    _Float16* dsts[8] = {catB0, catB0, catB0, catB1, catB1, catB2, catB2, catB2};
    int p = pair - cum[job];
    int KC = KCs[job], NC = NCs[job];
    int nt = p / KC, kc = p - nt * KC;
    int n = (nt >> 1) * 64 + ((lane & 31) * 2) + (nt & 1);
    int k0 = kc * 16 + (lane >> 5) * 8;
    const float* B = srcs[job];
    half8 o;
#pragma unroll
    for (int jj = 0; jj < 8; ++jj)
        o[jj] = (_Float16)B[(size_t)(k0 + jj) * NC + n];
    int ntG = ntb[job] + nt;
    *(half8*)(dsts[job] + (((size_t)ntG * KC + kc) * 64 + lane) * 8) = o;
}

// ------------------------------------------------------------------
// MFMA GEMM: block = 64 rows x 256 cols. All 4 waves share the SAME
// two A row-tiles (L1-resident); each wave owns one 64-col group.
// ------------------------------------------------------------------
__global__ __launch_bounds__(256) void gemm_mfma(
    const _Float16* __restrict__ Asw, const _Float16* __restrict__ Bsw,
    const float* __restrict__ bias, _Float16* __restrict__ C,
    int M, int K, int NC)
{
    const int wave = threadIdx.x >> 6, lane = threadIdx.x & 63;
    const int KC = K >> 4;
    const int rt0 = blockIdx.x * 2;       // 2 row-tiles (64 rows) per block
    const int NG = NC >> 6;
    int g = blockIdx.y * 4 + wave;        // one 64-col group per wave
    if (g >= NG) g = NG - 1;              // duplicate work for odd group counts

    const half8* Ap0 = (const half8*)Asw + (size_t)rt0 * KC * 64 + lane;
    const half8* Ap1 = Ap0 + (size_t)KC * 64;
    const half8* Bp0 = (const half8*)Bsw + (size_t)(2 * g) * KC * 64 + lane;
    const half8* Bp1 = Bp0 + (size_t)KC * 64;

    floatx16 accE0 = {0.f}, accE1 = {0.f}, accO0 = {0.f}, accO1 = {0.f};

#pragma unroll 4
    for (int kc = 0; kc < KC; ++kc) {
        half8 a0 = Ap0[(size_t)kc * 64];
        half8 a1 = Ap1[(size_t)kc * 64];
        half8 b0 = Bp0[(size_t)kc * 64];
        half8 b1 = Bp1[(size_t)kc * 64];
        accE0 = __builtin_amdgcn_mfma_f32_32x32x16_f16(a0, b0, accE0, 0, 0, 0);
        accE1 = __builtin_amdgcn_mfma_f32_32x32x16_f16(a1, b0, accE1, 0, 0, 0);
        accO0 = __builtin_amdgcn_mfma_f32_32x32x16_f16(a0, b1, accO0, 0, 0, 0);
        accO1 = __builtin_amdgcn_mfma_f32_32x32x16_f16(a1, b1, accO1, 0, 0, 0);
    }

    const int nlane = lane & 31, hs = lane >> 5;
    int colb = g * 64 + nlane * 2;
    float be = bias[colb], bo = bias[colb + 1];
#pragma unroll
    for (int r = 0; r < 16; ++r) {
        int rowin = (r & 3) + 8 * (r >> 2) + 4 * hs;
        int row0 = rt0 * 32 + rowin;
        int row1 = row0 + 32;
        if (row0 < M) {
            hv2 pe;
            pe[0] = (_Float16)(accE0[r] + be);
            pe[1] = (_Float16)(accO0[r] + bo);
            *(hv2*)(C + (size_t)row0 * NC + colb) = pe;
        }
        if (row1 < M) {
            hv2 po;
            po[0] = (_Float16)(accE1[r] + be);
            po[1] = (_Float16)(accO1[r] + bo);
            *(hv2*)(C + (size_t)row1 * NC + colb) = po;
        }
    }
}

// ------------------------------------------------------------------
// CSR build: histogram -> two-level scan -> scatter
// ------------------------------------------------------------------
__global__ __launch_bounds__(256) void hist_kernel(const int* __restrict__ dst,
                                                   int* __restrict__ deg)
{
    int e = blockIdx.x * 256 + threadIdx.x;
    if (e < EE) atomicAdd(&deg[dst[e]], 1);
}

__global__ __launch_bounds__(256) void scan_local(const int* __restrict__ deg,
                                                  int* __restrict__ rowoff,
                                                  int* __restrict__ part)
{
    __shared__ int sd[256];
    int tid = threadIdx.x;
    int i = blockIdx.x * 256 + tid;
    int v = (i < NN) ? deg[i] : 0;
    sd[tid] = v;
    __syncthreads();
    for (int off = 1; off < 256; off <<= 1) {
        int t = (tid >= off) ? sd[tid - off] : 0;
        __syncthreads();
        sd[tid] += t;
        __syncthreads();
    }
    if (i < NN) rowoff[i] = sd[tid] - v;
    if (tid == 255) part[blockIdx.x] = sd[255];
}

__global__ __launch_bounds__(256) void scan_part(int* __restrict__ part,
                                                 int* __restrict__ rowoff)
{
    __shared__ int sd[256];
    int tid = threadIdx.x;
    int v = (tid < NB) ? part[tid] : 0;
    sd[tid] = v;
    __syncthreads();
    for (int off = 1; off < 256; off <<= 1) {
        int t = (tid >= off) ? sd[tid - off] : 0;
        __syncthreads();
        sd[tid] += t;
        __syncthreads();
    }
    if (tid < NB) part[tid] = sd[tid] - v;
    if (tid == 0) rowoff[NN] = EE;
}

__global__ __launch_bounds__(256) void scan_add(int* __restrict__ rowoff,
                                                const int* __restrict__ part,
                                                int* __restrict__ cursor)
{
    int i = blockIdx.x * 256 + threadIdx.x;
    if (i < NN) {
        rowoff[i] += part[blockIdx.x];
        cursor[i] = 0;
    }
}

// scatter: CSR edge data. Two streams per edge:
//   sep: {src, bitcast(1/|Z|)} 8B ; apk: 4x duplicated-fp16 attrs 16B
__global__ __launch_bounds__(256) void scatter_kernel(
    const int* __restrict__ src, const int* __restrict__ dst,
    const float* __restrict__ ea, const int* __restrict__ rowoff,
    int* __restrict__ cursor, int2* __restrict__ sep,
    unsigned int* __restrict__ apk)
{
    int e = blockIdx.x * 256 + threadIdx.x;
    if (e < EE) {
        int d = dst[e];
        int pos = rowoff[d] + atomicAdd(&cursor[d], 1);
        const float* p = ea + (size_t)e * 5;
        int2 o2;
        o2.x = src[e];
        o2.y = __float_as_int(1.0f / fmaxf(p[3], 1e-6f));
        sep[pos] = o2;
        uint4 o;
        o.x = dup16(p[0]); o.y = dup16(p[1]);
        o.z = dup16(p[2]); o.w = dup16(p[3]);
        *(uint4*)(apk + (size_t)pos * 4) = o;
    }
}

// ------------------------------------------------------------------
// Fused GATv2 + LayerNorm + residual (+ELU) + A-swizzle for next GEMM.
// One wave per node; packed-fp16 score chain (round-2 proven structure).
// Physics term computed inline (branch-free, matches old table math):
//   q = temp/|Z|; c=max(q,64); qs=min(q,64); inv=64*rcp(c); sl=c*log2e/64
// h residual carried in fp16 (MODE0 writes h16, MODE1 reads it).
// ------------------------------------------------------------------
template<int MODE, int RSTRIDE>
__global__ __launch_bounds__(256) void fused_attn_ln(
    const int* __restrict__ rowoff, const int2* __restrict__ sep,
    const unsigned int* __restrict__ apk,
    const _Float16* __restrict__ xlp, const _Float16* __restrict__ Wh,
    const float* __restrict__ tmpP,
    const float* __restrict__ bias, const float* __restrict__ lnw,
    const float* __restrict__ lnb,
    const _Float16* __restrict__ residH, _Float16* __restrict__ h16,
    float* __restrict__ outF, _Float16* __restrict__ aswOut)
{
    int v = __builtin_amdgcn_readfirstlane(blockIdx.x * 4 + (threadIdx.x >> 6));
    int lane = threadIdx.x & 63;
    if (v >= NN) return;
    int grp = lane >> 4;
    int sub = lane & 15;
    int j = grp * 64 + sub * 4;

    hv4 ww0h = *(const hv4*)(Wh + j);
    hv4 ww1h = *(const hv4*)(Wh + 256 + j);
    hv4 ww2h = *(const hv4*)(Wh + 512 + j);
    hv4 ww3h = *(const hv4*)(Wh + 768 + j);
    hv4 ww4h = *(const hv4*)(Wh + 1024 + j);
    hv4 atvh = *(const hv4*)(Wh + 1280 + j);
    hv4 xrvh = *(const hv4*)(xlp + (size_t)v * RSTRIDE + 256 + j);
    const _Float16 s02 = (_Float16)0.2f;
    const hv4 sl02 = {s02, s02, s02, s02};
    const float L2E = 1.44269504088896340736f;
    float tmp = tmpP[0];

    float mxd = -INFINITY, dend = 0.f;
    fv4 acc = {0.f, 0.f, 0.f, 0.f};

    int beg = __builtin_amdgcn_readfirstlane(rowoff[v]);
    int end = __builtin_amdgcn_readfirstlane(rowoff[v + 1]);
    int i = beg;
    for (; i + 4 <= end; i += 4) {
        int s[4]; float er[4]; uint4 ap[4]; hv4 xh[4]; float l[4];
#pragma unroll
        for (int u = 0; u < 4; ++u) {
            int2 sv = sep[i + u];
            s[u] = __builtin_amdgcn_readfirstlane(sv.x);
            er[u] = __int_as_float(__builtin_amdgcn_readfirstlane(sv.y));
            ap[u] = *(const uint4*)(apk + (size_t)(i + u) * 4);
        }
#pragma unroll
        for (int u = 0; u < 4; ++u)
            xh[u] = *(const hv4*)(xlp + (size_t)s[u] * RSTRIDE + j);
        unsigned qpk[4], ipk[4]; float sl[4];
#pragma unroll
        for (int u = 0; u < 4; ++u) {
            float q = tmp * er[u];
            float c = fmaxf(q, 64.f);
            qpk[u] = duph(fminf(q, 64.f));
            ipk[u] = duph(64.f * __builtin_amdgcn_rcpf(c));
            sl[u] = c * (L2E / 64.f);
        }
#pragma unroll
        for (int u = 0; u < 4; ++u) {
            hv4 t = xh[u] + xrvh;                 // xl[src] + xr[dst]
            t += b4(ap[u].x) * ww0h;
            t += b4(ap[u].y) * ww1h;
            t += b4(ap[u].z) * ww2h;
            t += b4(ap[u].w) * ww3h;
            hv4 m = b4(qpk[u]) * ww4h;            // min(q,64)*ww4
            m += b4(ipk[u]) * t;                  // + inv_s*(...)
            hv4 mn = m * sl02;
            m = __builtin_elementwise_max(m, mn); // leaky_relu (homogeneous)
            l[u] = dot4h(m, atvh, 0.f);
        }
#pragma unroll
        for (int u = 0; u < 4; ++u)
            l[u] = red16(l[u]) * sl[u];           // * s*log2e
        float nm = fmaxf(fmaxf(l[0], l[1]), fmaxf(l[2], l[3]));
        nm = fmaxf(nm, mxd);
        float sc = fexp2(mxd - nm);
        float e0 = fexp2(l[0] - nm);
        float e1 = fexp2(l[1] - nm);
        float e2 = fexp2(l[2] - nm);
        float e3 = fexp2(l[3] - nm);
        mxd = nm;
        dend = dend * sc + ((e0 + e1) + (e2 + e3));
        hv4 X = xh[0] * b4(duph(e0));
        X += xh[1] * b4(duph(e1));
        X += xh[2] * b4(duph(e2));
        X += xh[3] * b4(duph(e3));
        fv4 Xf = __builtin_convertvector(X, fv4);
        acc = acc * sc + Xf;
    }
    for (; i < end; ++i) {
        int2 sv = sep[i];
        int s0 = __builtin_amdgcn_readfirstlane(sv.x);
        float er = __int_as_float(__builtin_amdgcn_readfirstlane(sv.y));
        uint4 ap = *(const uint4*)(apk + (size_t)i * 4);
        hv4 xh = *(const hv4*)(xlp + (size_t)s0 * RSTRIDE + j);
        float q = tmp * er;
        float c = fmaxf(q, 64.f);
        unsigned qpk = duph(fminf(q, 64.f));
        unsigned ipk = duph(64.f * __builtin_amdgcn_rcpf(c));
        float slv = c * (L2E / 64.f);
        hv4 t = xh + xrvh;
        t += b4(ap.x) * ww0h;
        t += b4(ap.y) * ww1h;
        t += b4(ap.z) * ww2h;
        t += b4(ap.w) * ww3h;
        hv4 m = b4(qpk) * ww4h;
        m += b4(ipk) * t;
        hv4 mn = m * sl02;
        m = __builtin_elementwise_max(m, mn);
        float l0 = dot4h(m, atvh, 0.f);
        l0 = red16(l0) * slv;
        float nm = fmaxf(mxd, l0);
        float sc = fexp2(mxd - nm);
        float e0 = fexp2(l0 - nm);
        mxd = nm;
        dend = dend * sc + e0;
        fv4 xf = __builtin_convertvector(xh, fv4);
        acc = acc * sc + xf * e0;
    }

    float inv = __builtin_amdgcn_rcpf(dend + 1e-16f);
    if (MODE <= 1) {
        fv4 bb = *(const fv4*)(bias + j);
        fv4 o = acc * inv + bb;
        float s  = (o[0] + o[1]) + (o[2] + o[3]);
        fv4 oq = o * o;
        float s2 = (oq[0] + oq[1]) + (oq[2] + oq[3]);
        s = red16(s);   s += __shfl_xor(s, 16, 64);  s += __shfl_xor(s, 32, 64);
        s2 = red16(s2); s2 += __shfl_xor(s2, 16, 64); s2 += __shfl_xor(s2, 32, 64);
        float mu = s * (1.f / 256.f);
        float var = s2 * (1.f / 256.f) - mu * mu;
        float rs = __builtin_amdgcn_rsqf(var + 1e-5f);
        fv4 lw = *(const fv4*)(lnw + j);
        fv4 lb = *(const fv4*)(lnb + j);
        fv4 rr;
        if (MODE == 0)
            rr = __builtin_convertvector(
                *(const hv4*)(residH + (size_t)v * RSTRIDE + j), fv4);
        else
            rr = __builtin_convertvector(
                *(const hv4*)(residH + (size_t)v * 256 + j), fv4);
        fv4 y = (o - mu) * rs * lw + lb + rr;
        y[0] = (y[0] > 0.f) ? y[0] : fexp2(y[0] * L2E) - 1.f;
        y[1] = (y[1] > 0.f) ? y[1] : fexp2(y[1] * L2E) - 1.f;
        y[2] = (y[2] > 0.f) ? y[2] : fexp2(y[2] * L2E) - 1.f;
        y[3] = (y[3] > 0.f) ? y[3] : fexp2(y[3] * L2E) - 1.f;
        hv4 yh = __builtin_convertvector(y, hv4);
        if (MODE == 0)
            *(hv4*)(h16 + (size_t)v * 256 + j) = yh;
        // fused A-swizzle for the next layer's GEMM (K=256, KC=16)
        int kc = j >> 4, half = (j >> 3) & 1, off = j & 7;
        size_t idx = (((size_t)(v >> 5) * 16 + kc) * 64 + (v & 31) + 32 * half) * 8 + off;
        *(hv4*)(aswOut + idx) = yh;
    } else {
        fv4 r = acc * inv;
        r[0] += __shfl_xor(r[0], 16, 64); r[0] += __shfl_xor(r[0], 32, 64);
        r[1] += __shfl_xor(r[1], 16, 64); r[1] += __shfl_xor(r[1], 32, 64);
        r[2] += __shfl_xor(r[2], 16, 64); r[2] += __shfl_xor(r[2], 32, 64);
        r[3] += __shfl_xor(r[3], 16, 64); r[3] += __shfl_xor(r[3], 32, 64);
        fv4 bb = *(const fv4*)(bias + sub * 4);
        fv4 o = r * 0.25f + bb;
        float s  = (o[0] + o[1]) + (o[2] + o[3]);
        fv4 oq = o * o;
        float s2 = (oq[0] + oq[1]) + (oq[2] + oq[3]);
        s = red16(s);
        s2 = red16(s2);
        float mu = s * (1.f / 64.f);
        float var = s2 * (1.f / 64.f) - mu * mu;
        float rs = __builtin_amdgcn_rsqf(var + 1e-5f);
        fv4 lw = *(const fv4*)(lnw + sub * 4);
        fv4 lb = *(const fv4*)(lnb + sub * 4);
        fv4 rr = __builtin_convertvector(
            *(const hv4*)(residH + (size_t)v * RSTRIDE + sub * 4), fv4);
        fv4 y = (o - mu) * rs * lw + lb + rr;
        if (grp == 0)
            *(fv4*)(outF + (size_t)v * 64 + sub * 4) = y;
    }
}

// ------------------------------------------------------------------
extern "C" void kernel_launch(void* const* d_in, const int* in_sizes, int n_in,
                              void* d_out, int out_size, void* d_ws, size_t ws_size,
                              hipStream_t stream)
{
    const float* x    = (const float*)d_in[0];
    const int*   eidx = (const int*)d_in[1];
    const float* ea   = (const float*)d_in[2];
    const int* src = eidx;
    const int* dst = eidx + EE;

    const float *Wl[3], *bl[3], *Wr[3], *br[3], *We[3], *att[3], *temp[3],
                *bias[3], *lnw[3], *lnb[3];
    for (int i = 0; i < 3; ++i) {
        int b = 3 + i * 10;
        Wl[i]   = (const float*)d_in[b + 0];
        bl[i]   = (const float*)d_in[b + 1];
        Wr[i]   = (const float*)d_in[b + 2];
        br[i]   = (const float*)d_in[b + 3];
        We[i]   = (const float*)d_in[b + 4];
        att[i]  = (const float*)d_in[b + 5];
        temp[i] = (const float*)d_in[b + 6];
        bias[i] = (const float*)d_in[b + 7];
        lnw[i]  = (const float*)d_in[b + 8];
        lnb[i]  = (const float*)d_in[b + 9];
    }
    const float* pw0 = (const float*)d_in[33];
    const float* pb0 = (const float*)d_in[34];
    const float* pw2 = (const float*)d_in[35];
    const float* pb2 = (const float*)d_in[36];

    // workspace carve-up
    char* w = (char*)d_ws;
    _Float16* h16 = (_Float16*)w; w += (size_t)NN * 256 * 2;      // 25.6 MB
    char*  gbase = w;         w += (size_t)NN * 256 * 4;          // Asw (<=25.7MB)
    _Float16* xlr = (_Float16*)w; w += (size_t)NN * 768 * 2;      // 76.8 MB
    unsigned int* apk = (unsigned int*)w; w += (size_t)EE * 16;   // fp16-pk attrs
    int2* sep    = (int2*)w;  w += (size_t)EE * 8;                // {src, erec}
    int* rowoff  = (int*)w;   w += (size_t)(NN + 16) * 4;
    int* cursor  = (int*)w;   w += (size_t)NN * 4;
    int* part    = (int*)w;   w += 1024;
    w = (char*)(((uintptr_t)w + 255) & ~(uintptr_t)255);
    _Float16* catB0 = (_Float16*)w; w += 196608;   // 24 nt x  8 kc x 512 h
    _Float16* catB1 = (_Float16*)w; w += 262144;   // 16 nt x 16 kc
    _Float16* catB2 = (_Float16*)w; w += 294912;   // 18 nt x 16 kc
    float* cb0 = (float*)w; w += 768 * 4;
    float* cb1 = (float*)w; w += 512 * 4;
    float* cb2 = (float*)w; w += 576 * 4;
    _Float16* Weh = (_Float16*)w; w += 4608 * 2;   // fp16 We+att, 3 layers
    _Float16* Asw = (_Float16*)gbase;              // max 25.62 MB used

    dim3 blk(256);
    dim3 grid_e((EE + 255) / 256);
    dim3 grid_nw((NN + 3) / 4);
    dim3 grid_nb(NB);
    const int MT2 = 782;   // ceil(50000/64) -> 64-row blocks

    // ---- CSR by dst (shared by all 3 layers) ----
    hipMemsetAsync(cursor, 0, (size_t)NN * 4, stream);
    hipLaunchKernelGGL(hist_kernel, grid_e, blk, 0, stream, dst, cursor);
    hipLaunchKernelGGL(scan_local, grid_nb, blk, 0, stream, cursor, rowoff, part);
    hipLaunchKernelGGL(scan_part, dim3(1), blk, 0, stream, part, rowoff);
    hipLaunchKernelGGL(scan_add, grid_nb, blk, 0, stream, rowoff, part, cursor);
    hipLaunchKernelGGL(scatter_kernel, grid_e, blk, 0, stream,
                       src, dst, ea, rowoff, cursor, sep, apk);

    // ---- all weight swizzles + bias concats + fp16 We/att, one dispatch ----
    hipLaunchKernelGGL(prep_weights, dim3(193), blk, 0, stream,
                       Wl[0], Wr[0], pw0, Wl[1], Wr[1], Wl[2], Wr[2], pw2,
                       catB0, catB1, catB2,
                       bl[0], br[0], pb0, bl[1], br[1], bl[2], br[2], pb2,
                       cb0, cb1, cb2,
                       We[0], We[1], We[2], att[0], att[1], att[2], Weh);

    // ---- Layer 0: swizzle x, one GEMM -> [xl|xr|res] fp16 rows of 768 ----
    swizzleA<<<dim3(1564, 2), blk, 0, stream>>>(x, Asw, NN, 128);
    gemm_mfma<<<dim3(MT2, 3), blk, 0, stream>>>(
        Asw, catB0, cb0, xlr, NN, 128, 768);
    fused_attn_ln<0, 768><<<grid_nw, blk, 0, stream>>>(
        rowoff, sep, apk, xlr, Weh, temp[0],
        bias[0], lnw[0], lnb[0], xlr + 512, h16, nullptr, Asw);

    // ---- Layer 1: one GEMM -> [xl|xr] rows of 512; resid = h16 ----
    gemm_mfma<<<dim3(MT2, 2), blk, 0, stream>>>(
        Asw, catB1, cb1, xlr, NN, 256, 512);
    fused_attn_ln<1, 512><<<grid_nw, blk, 0, stream>>>(
        rowoff, sep, apk, xlr, Weh + 1536, temp[1],
        bias[1], lnw[1], lnb[1], h16, nullptr, nullptr, Asw);

    // ---- Layer 2: single GEMM -> [xl|xr|res64] rows of 576 (9 groups) ----
    gemm_mfma<<<dim3(MT2, 3), blk, 0, stream>>>(
        Asw, catB2, cb2, xlr, NN, 256, 576);
    fused_attn_ln<2, 576><<<grid_nw, blk, 0, stream>>>(
        rowoff, sep, apk, xlr, Weh + 3072, temp[2],
        bias[2], lnw[2], lnb[2], xlr + 512, nullptr, (float*)d_out, nullptr);
}

// Round 8
// 613.734 us; speedup vs baseline: 1.0574x; 1.0207x over previous
//
#include <hip/hip_runtime.h>
#include <math.h>

#define NN 50000
#define EE 800000
#define NB 196   // ceil(NN/256)

typedef _Float16 half8 __attribute__((ext_vector_type(8)));
typedef _Float16 hv4  __attribute__((ext_vector_type(4)));
typedef _Float16 hv2  __attribute__((ext_vector_type(2)));
typedef __fp16 fp16v2 __attribute__((ext_vector_type(2)));
typedef float floatx16 __attribute__((ext_vector_type(16)));
typedef float fv4 __attribute__((ext_vector_type(4)));

__device__ __forceinline__ float fexp2(float x) { return __builtin_amdgcn_exp2f(x); }

// DPP row_ror all-reduce within 16-lane rows: rotations by 1,2,4,8.
template<int CTRL>
__device__ __forceinline__ float dppadd(float x) {
    int t = __builtin_amdgcn_update_dpp(0, __float_as_int(x), CTRL, 0xf, 0xf, false);
    return x + __int_as_float(t);
}
__device__ __forceinline__ float red16(float x) {
    x = dppadd<0x121>(x);   // row_ror:1
    x = dppadd<0x122>(x);   // row_ror:2
    x = dppadd<0x124>(x);   // row_ror:4
    x = dppadd<0x128>(x);   // row_ror:8
    return x;
}

// fp16 helpers -----------------------------------------------------
// RTN duplicated-pack (accuracy path, used in prep/scatter/table kernels)
__device__ __forceinline__ unsigned int dup16(float x) {
    unsigned short b = __builtin_bit_cast(unsigned short, (_Float16)x);
    return (unsigned int)b * 0x10001u;
}
// fast duplicated-pack (hot loop, RTZ ok)
__device__ __forceinline__ unsigned int duph(float x) {
#if __has_builtin(__builtin_amdgcn_cvt_pkrtz)
    fp16v2 p = __builtin_amdgcn_cvt_pkrtz(x, x);
    return __builtin_bit_cast(unsigned int, p);
#else
    return dup16(x);
#endif
}
// broadcast a packed half2 dword to an hv4 (ISel reuses the same dword)
__device__ __forceinline__ hv4 b4(unsigned int u) {
    hv2 p = __builtin_bit_cast(hv2, u);
    return (hv4){p[0], p[1], p[0], p[1]};
}
// 4-element fp16 dot accumulating into f32 (v_dot2_f32_f16 x2)
__device__ __forceinline__ float dot4h(hv4 a, hv4 b, float c) {
    hv2 al = {a[0], a[1]}, ah = {a[2], a[3]};
    hv2 bl = {b[0], b[1]}, bh = {b[2], b[3]};
#if __has_builtin(__builtin_amdgcn_fdot2)
    return __builtin_amdgcn_fdot2(al, bl, __builtin_amdgcn_fdot2(ah, bh, c, false), false);
#else
    return c + (float)a[0]*(float)b[0] + (float)a[1]*(float)b[1]
             + (float)a[2]*(float)b[2] + (float)a[3]*(float)b[3];
#endif
}

// ------------------------------------------------------------------
// Swizzle A (fp32 row-major M x K) into 32x32x16 MFMA A-fragment order.
// ------------------------------------------------------------------
__global__ __launch_bounds__(256) void swizzleA(
    const float* __restrict__ A, _Float16* __restrict__ Asw, int M, int K)
{
    int wave = threadIdx.x >> 6, lane = threadIdx.x & 63;
    int tile = blockIdx.x;
    int kc = blockIdx.y * 4 + wave;
    int KC = K >> 4;
    if (kc >= KC) return;
    int row = tile * 32 + (lane & 31);
    int k0 = kc * 16 + (lane >> 5) * 8;
    float4 v0 = make_float4(0.f, 0.f, 0.f, 0.f);
    float4 v1 = make_float4(0.f, 0.f, 0.f, 0.f);
    if (row < M) {
        const float* p = A + (size_t)row * K + k0;
        v0 = *(const float4*)p;
        v1 = *(const float4*)(p + 4);
    }
    half8 o;
    o[0] = (_Float16)v0.x; o[1] = (_Float16)v0.y;
    o[2] = (_Float16)v0.z; o[3] = (_Float16)v0.w;
    o[4] = (_Float16)v1.x; o[5] = (_Float16)v1.y;
    o[6] = (_Float16)v1.z; o[7] = (_Float16)v1.w;
    *(half8*)(Asw + (((size_t)tile * KC + kc) * 64 + lane) * 8) = o;
}

// ------------------------------------------------------------------
// All weight swizzles + bias concats + fp16 We/att conversion, one dispatch.
// ------------------------------------------------------------------
__global__ __launch_bounds__(256) void prep_weights(
    const float* __restrict__ s0, const float* __restrict__ s1,
    const float* __restrict__ s2, const float* __restrict__ s3,
    const float* __restrict__ s4, const float* __restrict__ s5,
    const float* __restrict__ s6, const float* __restrict__ s7,
    _Float16* __restrict__ catB0, _Float16* __restrict__ catB1,
    _Float16* __restrict__ catB2,
    const float* __restrict__ bl0, const float* __restrict__ br0,
    const float* __restrict__ pb0, const float* __restrict__ bl1,
    const float* __restrict__ br1, const float* __restrict__ bl2,
    const float* __restrict__ br2, const float* __restrict__ pb2,
    float* __restrict__ cb0, float* __restrict__ cb1, float* __restrict__ cb2,
    const float* __restrict__ We0a, const float* __restrict__ We1a,
    const float* __restrict__ We2a, const float* __restrict__ att0a,
    const float* __restrict__ att1a, const float* __restrict__ att2a,
    _Float16* __restrict__ Weh)
{
    int b = blockIdx.x;
    if (b == 192) {   // fp16 conversion of We (1280) + att (256) per layer
        const float* Ws[3] = {We0a, We1a, We2a};
        const float* As[3] = {att0a, att1a, att2a};
        for (int t = threadIdx.x; t < 4608; t += 256) {
            int l = t / 1536, o = t - l * 1536;
            float v = (o < 1280) ? Ws[l][o] : As[l][o - 1280];
            Weh[t] = (_Float16)v;
        }
        return;
    }
    if (b >= 184) {
        int t = (b - 184) * 256 + threadIdx.x;   // 0..2047
        if (t < 768) {
            cb0[t] = (t < 256) ? bl0[t] : (t < 512) ? br0[t - 256] : pb0[t - 512];
        } else if (t < 1280) {
            int u = t - 768;
            cb1[u] = (u < 256) ? bl1[u] : br1[u - 256];
        } else if (t < 1856) {
            int u = t - 1280;
            cb2[u] = (u < 256) ? bl2[u] : (u < 512) ? br2[u - 256] : pb2[u - 512];
        }
        return;
    }
    int wave = threadIdx.x >> 6, lane = threadIdx.x & 63;
    int pair = b * 4 + wave;     // 0..735
    const int cum[9] = {0, 64, 128, 192, 320, 448, 576, 704, 736};
    int job = 0;
    while (pair >= cum[job + 1]) ++job;
    const float* srcs[8] = {s0, s1, s2, s3, s4, s5, s6, s7};
    const int KCs[8] = {8, 8, 8, 16, 16, 16, 16, 16};
    const int NCs[8] = {256, 256, 256, 256, 256, 256, 256, 64};
    const int ntb[8] = {0, 8, 16, 0, 8, 0, 8, 16};
    _Float16* dsts[8] = {catB0, catB0, catB0, catB1, catB1, catB2, catB2, catB2};
    int p = pair - cum[job];
    int KC = KCs[job], NC = NCs[job];
    int nt = p / KC, kc = p - nt * KC;
    int n = (nt >> 1) * 64 + ((lane & 31) * 2) + (nt & 1);
    int k0 = kc * 16 + (lane >> 5) * 8;
    const float* B = srcs[job];
    half8 o;
#pragma unroll
    for (int jj = 0; jj < 8; ++jj)
        o[jj] = (_Float16)B[(size_t)(k0 + jj) * NC + n];
    int ntG = ntb[job] + nt;
    *(half8*)(dsts[job] + (((size_t)ntG * KC + kc) * 64 + lane) * 8) = o;
}

// ------------------------------------------------------------------
// MFMA GEMM: block = 64 rows x 256 cols. All 4 waves share the SAME
// two A row-tiles (L1-resident); each wave owns one 64-col group.
// ------------------------------------------------------------------
__global__ __launch_bounds__(256) void gemm_mfma(
    const _Float16* __restrict__ Asw, const _Float16* __restrict__ Bsw,
    const float* __restrict__ bias, _Float16* __restrict__ C,
    int M, int K, int NC)
{
    const int wave = threadIdx.x >> 6, lane = threadIdx.x & 63;
    const int KC = K >> 4;
    const int rt0 = blockIdx.x * 2;       // 2 row-tiles (64 rows) per block
    const int NG = NC >> 6;
    int g = blockIdx.y * 4 + wave;        // one 64-col group per wave
    if (g >= NG) g = NG - 1;              // duplicate work for odd group counts

    const half8* Ap0 = (const half8*)Asw + (size_t)rt0 * KC * 64 + lane;
    const half8* Ap1 = Ap0 + (size_t)KC * 64;
    const half8* Bp0 = (const half8*)Bsw + (size_t)(2 * g) * KC * 64 + lane;
    const half8* Bp1 = Bp0 + (size_t)KC * 64;

    floatx16 accE0 = {0.f}, accE1 = {0.f}, accO0 = {0.f}, accO1 = {0.f};

#pragma unroll 4
    for (int kc = 0; kc < KC; ++kc) {
        half8 a0 = Ap0[(size_t)kc * 64];
        half8 a1 = Ap1[(size_t)kc * 64];
        half8 b0 = Bp0[(size_t)kc * 64];
        half8 b1 = Bp1[(size_t)kc * 64];
        accE0 = __builtin_amdgcn_mfma_f32_32x32x16_f16(a0, b0, accE0, 0, 0, 0);
        accE1 = __builtin_amdgcn_mfma_f32_32x32x16_f16(a1, b0, accE1, 0, 0, 0);
        accO0 = __builtin_amdgcn_mfma_f32_32x32x16_f16(a0, b1, accO0, 0, 0, 0);
        accO1 = __builtin_amdgcn_mfma_f32_32x32x16_f16(a1, b1, accO1, 0, 0, 0);
    }

    const int nlane = lane & 31, hs = lane >> 5;
    int colb = g * 64 + nlane * 2;
    float be = bias[colb], bo = bias[colb + 1];
#pragma unroll
    for (int r = 0; r < 16; ++r) {
        int rowin = (r & 3) + 8 * (r >> 2) + 4 * hs;
        int row0 = rt0 * 32 + rowin;
        int row1 = row0 + 32;
        if (row0 < M) {
            hv2 pe;
            pe[0] = (_Float16)(accE0[r] + be);
            pe[1] = (_Float16)(accO0[r] + bo);
            *(hv2*)(C + (size_t)row0 * NC + colb) = pe;
        }
        if (row1 < M) {
            hv2 po;
            po[0] = (_Float16)(accE1[r] + be);
            po[1] = (_Float16)(accO1[r] + bo);
            *(hv2*)(C + (size_t)row1 * NC + colb) = po;
        }
    }
}

// ------------------------------------------------------------------
// CSR build: histogram -> two-level scan -> scatter
// ------------------------------------------------------------------
__global__ __launch_bounds__(256) void hist_kernel(const int* __restrict__ dst,
                                                   int* __restrict__ deg)
{
    int e = blockIdx.x * 256 + threadIdx.x;
    if (e < EE) atomicAdd(&deg[dst[e]], 1);
}

__global__ __launch_bounds__(256) void scan_local(const int* __restrict__ deg,
                                                  int* __restrict__ rowoff,
                                                  int* __restrict__ part)
{
    __shared__ int sd[256];
    int tid = threadIdx.x;
    int i = blockIdx.x * 256 + tid;
    int v = (i < NN) ? deg[i] : 0;
    sd[tid] = v;
    __syncthreads();
    for (int off = 1; off < 256; off <<= 1) {
        int t = (tid >= off) ? sd[tid - off] : 0;
        __syncthreads();
        sd[tid] += t;
        __syncthreads();
    }
    if (i < NN) rowoff[i] = sd[tid] - v;
    if (tid == 255) part[blockIdx.x] = sd[255];
}

__global__ __launch_bounds__(256) void scan_part(int* __restrict__ part,
                                                 int* __restrict__ rowoff)
{
    __shared__ int sd[256];
    int tid = threadIdx.x;
    int v = (tid < NB) ? part[tid] : 0;
    sd[tid] = v;
    __syncthreads();
    for (int off = 1; off < 256; off <<= 1) {
        int t = (tid >= off) ? sd[tid - off] : 0;
        __syncthreads();
        sd[tid] += t;
        __syncthreads();
    }
    if (tid < NB) part[tid] = sd[tid] - v;
    if (tid == 0) rowoff[NN] = EE;
}

__global__ __launch_bounds__(256) void scan_add(int* __restrict__ rowoff,
                                                const int* __restrict__ part,
                                                int* __restrict__ cursor)
{
    int i = blockIdx.x * 256 + threadIdx.x;
    if (i < NN) {
        rowoff[i] += part[blockIdx.x];
        cursor[i] = 0;
    }
}

// scatter: CSR edge data. Two streams per edge:
//   sep: {src, bitcast(1/|Z|)} 8B ; apk: 4x duplicated-fp16 attrs 16B
__global__ __launch_bounds__(256) void scatter_kernel(
    const int* __restrict__ src, const int* __restrict__ dst,
    const float* __restrict__ ea, const int* __restrict__ rowoff,
    int* __restrict__ cursor, int2* __restrict__ sep,
    unsigned int* __restrict__ apk)
{
    int e = blockIdx.x * 256 + threadIdx.x;
    if (e < EE) {
        int d = dst[e];
        int pos = rowoff[d] + atomicAdd(&cursor[d], 1);
        const float* p = ea + (size_t)e * 5;
        int2 o2;
        o2.x = src[e];
        o2.y = __float_as_int(1.0f / fmaxf(p[3], 1e-6f));
        sep[pos] = o2;
        uint4 o;
        o.x = dup16(p[0]); o.y = dup16(p[1]);
        o.z = dup16(p[2]); o.w = dup16(p[3]);
        *(uint4*)(apk + (size_t)pos * 4) = o;
    }
}

// ------------------------------------------------------------------
// Physics-term tables (q = temp/|Z| unbounded -> homogeneity rescale
// s = max(1, q/64)):
//   m' = inv_s*(xl+xr+sum ak*wwk) + min(q,64)*ww4 ; logit = s*dot(att,LR(m'))
// Record {qs_pk, inv_pk, s*log2e (f32), pad} = 16 B. Builds one or two
// layer tables per dispatch (qB may be null).
// ------------------------------------------------------------------
__global__ __launch_bounds__(256) void build_qtab(
    const int2* __restrict__ sep,
    const float* __restrict__ tA, unsigned int* __restrict__ qA,
    const float* __restrict__ tB, unsigned int* __restrict__ qB)
{
    int e = blockIdx.x * 256 + threadIdx.x;
    if (e >= EE) return;
    float er = __int_as_float(sep[e].y);
    {
        float q = tA[0] * er;
        float qs = fminf(q, 64.f);
        float inv = (q > 64.f) ? 64.f * __builtin_amdgcn_rcpf(q) : 1.0f;
        float sl = fmaxf(q * 0.015625f, 1.f) * 1.44269504088896340736f;
        uint4 o;
        o.x = dup16(qs);
        o.y = dup16(inv);
        o.z = __builtin_bit_cast(unsigned int, sl);
        o.w = 0u;
        *(uint4*)(qA + (size_t)e * 4) = o;
    }
    if (qB) {
        float q = tB[0] * er;
        float qs = fminf(q, 64.f);
        float inv = (q > 64.f) ? 64.f * __builtin_amdgcn_rcpf(q) : 1.0f;
        float sl = fmaxf(q * 0.015625f, 1.f) * 1.44269504088896340736f;
        uint4 o;
        o.x = dup16(qs);
        o.y = dup16(inv);
        o.z = __builtin_bit_cast(unsigned int, sl);
        o.w = 0u;
        *(uint4*)(qB + (size_t)e * 4) = o;
    }
}

// ------------------------------------------------------------------
// Fused GATv2 + LayerNorm + residual (+ELU) + A-swizzle for next GEMM.
// One wave per node; packed-fp16 score chain (round-2 proven loop).
// Plain loads/stores only (NT hints measured to corrupt results on
// this target -- rounds 6/7 NaN, reverted).
// ------------------------------------------------------------------
template<int MODE, int RSTRIDE>
__global__ __launch_bounds__(256) void fused_attn_ln(
    const int* __restrict__ rowoff, const int2* __restrict__ sep,
    const unsigned int* __restrict__ apk, const unsigned int* __restrict__ qtab,
    const _Float16* __restrict__ xlp, const _Float16* __restrict__ Wh,
    const float* __restrict__ bias, const float* __restrict__ lnw,
    const float* __restrict__ lnb,
    const _Float16* __restrict__ residH, _Float16* __restrict__ h16,
    float* __restrict__ outF, _Float16* __restrict__ aswOut)
{
    int v = __builtin_amdgcn_readfirstlane(blockIdx.x * 4 + (threadIdx.x >> 6));
    int lane = threadIdx.x & 63;
    if (v >= NN) return;
    int grp = lane >> 4;
    int sub = lane & 15;
    int j = grp * 64 + sub * 4;

    hv4 ww0h = *(const hv4*)(Wh + j);
    hv4 ww1h = *(const hv4*)(Wh + 256 + j);
    hv4 ww2h = *(const hv4*)(Wh + 512 + j);
    hv4 ww3h = *(const hv4*)(Wh + 768 + j);
    hv4 ww4h = *(const hv4*)(Wh + 1024 + j);
    hv4 atvh = *(const hv4*)(Wh + 1280 + j);
    hv4 xrvh = *(const hv4*)(xlp + (size_t)v * RSTRIDE + 256 + j);
    const _Float16 s02 = (_Float16)0.2f;
    const hv4 sl02 = {s02, s02, s02, s02};
    const float L2E = 1.44269504088896340736f;

    float mxd = -INFINITY, dend = 0.f;
    fv4 acc = {0.f, 0.f, 0.f, 0.f};

    int beg = __builtin_amdgcn_readfirstlane(rowoff[v]);
    int end = __builtin_amdgcn_readfirstlane(rowoff[v + 1]);
    int i = beg;
    for (; i + 4 <= end; i += 4) {
        int s[4]; uint4 ap[4], qt[4]; hv4 xh[4]; float l[4];
#pragma unroll
        for (int u = 0; u < 4; ++u) {
            int2 sv = sep[i + u];
            s[u] = __builtin_amdgcn_readfirstlane(sv.x);
            ap[u] = *(const uint4*)(apk + (size_t)(i + u) * 4);
            qt[u] = *(const uint4*)(qtab + (size_t)(i + u) * 4);
        }
#pragma unroll
        for (int u = 0; u < 4; ++u)
            xh[u] = *(const hv4*)(xlp + (size_t)s[u] * RSTRIDE + j);
#pragma unroll
        for (int u = 0; u < 4; ++u) {
            hv4 t = xh[u] + xrvh;                 // xl[src] + xr[dst]
            t += b4(ap[u].x) * ww0h;
            t += b4(ap[u].y) * ww1h;
            t += b4(ap[u].z) * ww2h;
            t += b4(ap[u].w) * ww3h;
            hv4 m = b4(qt[u].x) * ww4h;           // min(q,64)*ww4
            m += b4(qt[u].y) * t;                 // + inv_s*(...)
            hv4 mn = m * sl02;
            m = __builtin_elementwise_max(m, mn); // leaky_relu (homogeneous)
            l[u] = dot4h(m, atvh, 0.f);
        }
#pragma unroll
        for (int u = 0; u < 4; ++u)
            l[u] = red16(l[u]) * __builtin_bit_cast(float, qt[u].z);  // *s*log2e
        float nm = fmaxf(fmaxf(l[0], l[1]), fmaxf(l[2], l[3]));
        nm = fmaxf(nm, mxd);
        float sc = fexp2(mxd - nm);
        float e0 = fexp2(l[0] - nm);
        float e1 = fexp2(l[1] - nm);
        float e2 = fexp2(l[2] - nm);
        float e3 = fexp2(l[3] - nm);
        mxd = nm;
        dend = dend * sc + ((e0 + e1) + (e2 + e3));
        hv4 X = xh[0] * b4(duph(e0));
        X += xh[1] * b4(duph(e1));
        X += xh[2] * b4(duph(e2));
        X += xh[3] * b4(duph(e3));
        fv4 Xf = __builtin_convertvector(X, fv4);
        acc = acc * sc + Xf;
    }
    for (; i < end; ++i) {
        int2 sv = sep[i];
        int s0 = __builtin_amdgcn_readfirstlane(sv.x);
        uint4 ap = *(const uint4*)(apk + (size_t)i * 4);
        uint4 qt = *(const uint4*)(qtab + (size_t)i * 4);
        hv4 xh = *(const hv4*)(xlp + (size_t)s0 * RSTRIDE + j);
        hv4 t = xh + xrvh;
        t += b4(ap.x) * ww0h;
        t += b4(ap.y) * ww1h;
        t += b4(ap.z) * ww2h;
        t += b4(ap.w) * ww3h;
        hv4 m = b4(qt.x) * ww4h;
        m += b4(qt.y) * t;
        hv4 mn = m * sl02;
        m = __builtin_elementwise_max(m, mn);
        float l0 = dot4h(m, atvh, 0.f);
        l0 = red16(l0) * __builtin_bit_cast(float, qt.z);
        float nm = fmaxf(mxd, l0);
        float sc = fexp2(mxd - nm);
        float e0 = fexp2(l0 - nm);
        mxd = nm;
        dend = dend * sc + e0;
        fv4 xf = __builtin_convertvector(xh, fv4);
        acc = acc * sc + xf * e0;
    }

    float inv = __builtin_amdgcn_rcpf(dend + 1e-16f);
    if (MODE <= 1) {
        fv4 bb = *(const fv4*)(bias + j);
        fv4 o = acc * inv + bb;
        float s  = (o[0] + o[1]) + (o[2] + o[3]);
        fv4 oq = o * o;
        float s2 = (oq[0] + oq[1]) + (oq[2] + oq[3]);
        s = red16(s);   s += __shfl_xor(s, 16, 64);  s += __shfl_xor(s, 32, 64);
        s2 = red16(s2); s2 += __shfl_xor(s2, 16, 64); s2 += __shfl_xor(s2, 32, 64);
        float mu = s * (1.f / 256.f);
        float var = s2 * (1.f / 256.f) - mu * mu;
        float rs = __builtin_amdgcn_rsqf(var + 1e-5f);
        fv4 lw = *(const fv4*)(lnw + j);
        fv4 lb = *(const fv4*)(lnb + j);
        fv4 rr;
        if (MODE == 0)
            rr = __builtin_convertvector(
                *(const hv4*)(residH + (size_t)v * RSTRIDE + j), fv4);
        else
            rr = __builtin_convertvector(
                *(const hv4*)(residH + (size_t)v * 256 + j), fv4);
        fv4 y = (o - mu) * rs * lw + lb + rr;
        y[0] = (y[0] > 0.f) ? y[0] : fexp2(y[0] * L2E) - 1.f;
        y[1] = (y[1] > 0.f) ? y[1] : fexp2(y[1] * L2E) - 1.f;
        y[2] = (y[2] > 0.f) ? y[2] : fexp2(y[2] * L2E) - 1.f;
        y[3] = (y[3] > 0.f) ? y[3] : fexp2(y[3] * L2E) - 1.f;
        hv4 yh = __builtin_convertvector(y, hv4);
        if (MODE == 0)
            *(hv4*)(h16 + (size_t)v * 256 + j) = yh;
        // fused A-swizzle for the next layer's GEMM (K=256, KC=16)
        int kc = j >> 4, half = (j >> 3) & 1, off = j & 7;
        size_t idx = (((size_t)(v >> 5) * 16 + kc) * 64 + (v & 31) + 32 * half) * 8 + off;
        *(hv4*)(aswOut + idx) = yh;
    } else {
        fv4 r = acc * inv;
        r[0] += __shfl_xor(r[0], 16, 64); r[0] += __shfl_xor(r[0], 32, 64);
        r[1] += __shfl_xor(r[1], 16, 64); r[1] += __shfl_xor(r[1], 32, 64);
        r[2] += __shfl_xor(r[2], 16, 64); r[2] += __shfl_xor(r[2], 32, 64);
        r[3] += __shfl_xor(r[3], 16, 64); r[3] += __shfl_xor(r[3], 32, 64);
        fv4 bb = *(const fv4*)(bias + sub * 4);
        fv4 o = r * 0.25f + bb;
        float s  = (o[0] + o[1]) + (o[2] + o[3]);
        fv4 oq = o * o;
        float s2 = (oq[0] + oq[1]) + (oq[2] + oq[3]);
        s = red16(s);
        s2 = red16(s2);
        float mu = s * (1.f / 64.f);
        float var = s2 * (1.f / 64.f) - mu * mu;
        float rs = __builtin_amdgcn_rsqf(var + 1e-5f);
        fv4 lw = *(const fv4*)(lnw + sub * 4);
        fv4 lb = *(const fv4*)(lnb + sub * 4);
        fv4 rr = __builtin_convertvector(
            *(const hv4*)(residH + (size_t)v * RSTRIDE + sub * 4), fv4);
        fv4 y = (o - mu) * rs * lw + lb + rr;
        if (grp == 0)
            *(fv4*)(outF + (size_t)v * 64 + sub * 4) = y;
    }
}

// ------------------------------------------------------------------
extern "C" void kernel_launch(void* const* d_in, const int* in_sizes, int n_in,
                              void* d_out, int out_size, void* d_ws, size_t ws_size,
                              hipStream_t stream)
{
    const float* x    = (const float*)d_in[0];
    const int*   eidx = (const int*)d_in[1];
    const float* ea   = (const float*)d_in[2];
    const int* src = eidx;
    const int* dst = eidx + EE;

    const float *Wl[3], *bl[3], *Wr[3], *br[3], *We[3], *att[3], *temp[3],
                *bias[3], *lnw[3], *lnb[3];
    for (int i = 0; i < 3; ++i) {
        int b = 3 + i * 10;
        Wl[i]   = (const float*)d_in[b + 0];
        bl[i]   = (const float*)d_in[b + 1];
        Wr[i]   = (const float*)d_in[b + 2];
        br[i]   = (const float*)d_in[b + 3];
        We[i]   = (const float*)d_in[b + 4];
        att[i]  = (const float*)d_in[b + 5];
        temp[i] = (const float*)d_in[b + 6];
        bias[i] = (const float*)d_in[b + 7];
        lnw[i]  = (const float*)d_in[b + 8];
        lnb[i]  = (const float*)d_in[b + 9];
    }
    const float* pw0 = (const float*)d_in[33];
    const float* pb0 = (const float*)d_in[34];
    const float* pw2 = (const float*)d_in[35];
    const float* pb2 = (const float*)d_in[36];

    // workspace carve-up
    char* w = (char*)d_ws;
    _Float16* h16 = (_Float16*)w; w += (size_t)NN * 256 * 2;      // 25.6 MB
    char*  gbase = w;         w += (size_t)NN * 256 * 4;          // Asw + qtab slot
    _Float16* xlr = (_Float16*)w; w += (size_t)NN * 768 * 2;      // 76.8 MB
    unsigned int* apk = (unsigned int*)w; w += (size_t)EE * 16;   // fp16-pk attrs
    int2* sep    = (int2*)w;  w += (size_t)EE * 8;                // {src, erec}
    unsigned int* qtab1 = (unsigned int*)w; w += (size_t)EE * 16; // layer-1 table
    int* rowoff  = (int*)w;   w += (size_t)(NN + 16) * 4;
    int* cursor  = (int*)w;   w += (size_t)NN * 4;
    int* part    = (int*)w;   w += 1024;
    w = (char*)(((uintptr_t)w + 255) & ~(uintptr_t)255);
    _Float16* catB0 = (_Float16*)w; w += 196608;   // 24 nt x  8 kc x 512 h
    _Float16* catB1 = (_Float16*)w; w += 262144;   // 16 nt x 16 kc
    _Float16* catB2 = (_Float16*)w; w += 294912;   // 18 nt x 16 kc
    float* cb0 = (float*)w; w += 768 * 4;
    float* cb1 = (float*)w; w += 512 * 4;
    float* cb2 = (float*)w; w += 576 * 4;
    _Float16* Weh = (_Float16*)w; w += 4608 * 2;   // fp16 We+att, 3 layers
    _Float16* Asw = (_Float16*)gbase;              // K=256 extents: wr 25,607,934 / rd 25,624,576 B
    // qtab slot placed past BOTH Asw extents; ends at 38.8 MB < 51.2 MB
    // region end. Used as layer-0 table, then rebuilt as layer-2 table
    // after fused<0> has consumed it (stream-ordered).
    unsigned int* qslot = (unsigned int*)(gbase + 26000000);

    dim3 blk(256);
    dim3 grid_e((EE + 255) / 256);
    dim3 grid_nw((NN + 3) / 4);
    dim3 grid_nb(NB);
    const int MT2 = 782;   // ceil(50000/64) -> 64-row blocks

    // ---- CSR by dst (shared by all 3 layers) ----
    hipMemsetAsync(cursor, 0, (size_t)NN * 4, stream);
    hipLaunchKernelGGL(hist_kernel, grid_e, blk, 0, stream, dst, cursor);
    hipLaunchKernelGGL(scan_local, grid_nb, blk, 0, stream, cursor, rowoff, part);
    hipLaunchKernelGGL(scan_part, dim3(1), blk, 0, stream, part, rowoff);
    hipLaunchKernelGGL(scan_add, grid_nb, blk, 0, stream, rowoff, part, cursor);
    hipLaunchKernelGGL(scatter_kernel, grid_e, blk, 0, stream,
                       src, dst, ea, rowoff, cursor, sep, apk);

    // ---- layer-0 + layer-1 physics tables, one dispatch ----
    hipLaunchKernelGGL(build_qtab, grid_e, blk, 0, stream,
                       sep, temp[0], qslot, temp[1], qtab1);

    // ---- all weight swizzles + bias concats + fp16 We/att, one dispatch ----
    hipLaunchKernelGGL(prep_weights, dim3(193), blk, 0, stream,
                       Wl[0], Wr[0], pw0, Wl[1], Wr[1], Wl[2], Wr[2], pw2,
                       catB0, catB1, catB2,
                       bl[0], br[0], pb0, bl[1], br[1], bl[2], br[2], pb2,
                       cb0, cb1, cb2,
                       We[0], We[1], We[2], att[0], att[1], att[2], Weh);

    // ---- Layer 0: swizzle x, one GEMM -> [xl|xr|res] fp16 rows of 768 ----
    swizzleA<<<dim3(1564, 2), blk, 0, stream>>>(x, Asw, NN, 128);
    gemm_mfma<<<dim3(MT2, 3), blk, 0, stream>>>(
        Asw, catB0, cb0, xlr, NN, 128, 768);
    fused_attn_ln<0, 768><<<grid_nw, blk, 0, stream>>>(
        rowoff, sep, apk, qslot, xlr, Weh,
        bias[0], lnw[0], lnb[0], xlr + 512, h16, nullptr, Asw);

    // ---- rebuild qslot as the layer-2 table (layer-0 table now dead) ----
    hipLaunchKernelGGL(build_qtab, grid_e, blk, 0, stream,
                       sep, temp[2], qslot, nullptr, nullptr);

    // ---- Layer 1: one GEMM -> [xl|xr] rows of 512; resid = h16 ----
    gemm_mfma<<<dim3(MT2, 2), blk, 0, stream>>>(
        Asw, catB1, cb1, xlr, NN, 256, 512);
    fused_attn_ln<1, 512><<<grid_nw, blk, 0, stream>>>(
        rowoff, sep, apk, qtab1, xlr, Weh + 1536,
        bias[1], lnw[1], lnb[1], h16, nullptr, nullptr, Asw);

    // ---- Layer 2: single GEMM -> [xl|xr|res64] rows of 576 (9 groups) ----
    gemm_mfma<<<dim3(MT2, 3), blk, 0, stream>>>(
        Asw, catB2, cb2, xlr, NN, 256, 576);
    fused_attn_ln<2, 576><<<grid_nw, blk, 0, stream>>>(
        rowoff, sep, apk, qslot, xlr, Weh + 3072,
        bias[2], lnw[2], lnb[2], xlr + 512, nullptr, (float*)d_out, nullptr);
}